// Round 14
// baseline (196.422 us; speedup 1.0000x reference)
//
#include <hip/hip_runtime.h>

#define BB   256
#define NIMG 49
#define NGPS 32
#define DIM  256
#define MPAD 64

typedef __attribute__((ext_vector_type(8))) __bf16 bf16x8;
typedef __attribute__((ext_vector_type(4))) float  f32x4;
typedef __attribute__((ext_vector_type(4))) unsigned int u32x4;

__device__ inline unsigned short f2bf(float f) {
  unsigned int u = __float_as_uint(f);
  u += 0x7fff + ((u >> 16) & 1);   // round-to-nearest-even
  return (unsigned short)(u >> 16);
}

__device__ inline float max3f(float a, float b, float c) {
  return fmaxf(fmaxf(a, b), c);    // clang folds to v_max3_f32
}

// DPP cross-lane reduce helpers (VALU pipe, no DS traffic).
template<int CTRL>
__device__ inline float dppmax(float v) {
  float o = __int_as_float(__builtin_amdgcn_update_dpp(0, __float_as_int(v), CTRL, 0xF, 0xF, true));
  return fmaxf(v, o);
}
template<int CTRL>
__device__ inline float dppadd(float v) {
  float o = __int_as_float(__builtin_amdgcn_update_dpp(0, __float_as_int(v), CTRL, 0xF, 0xF, true));
  return v + o;
}
__device__ inline float max16(float v) {   // max across the 16 lanes of a DPP row
  v = dppmax<0xB1>(v); v = dppmax<0x4E>(v); v = dppmax<0x141>(v); v = dppmax<0x140>(v);
  return v;
}
__device__ inline float sum16(float v) {   // sum across the 16 lanes of a DPP row
  v = dppadd<0xB1>(v); v = dppadd<0x4E>(v); v = dppadd<0x141>(v); v = dppadd<0x140>(v);
  return v;
}

// ---------------- kernel 1: L2-normalize + cast to bf16, FRAGMENT-CONTIGUOUS layout --
// (r9 win: +44%. Every hot-loop global load is `lane i reads base + i*16B`.)
//   imgS[b][chunk s=0..31][row 0..63][8 bf16]  (b stride 16384 elem)
//   gpsS[g][mt][kc][grp*16+c][8 bf16]          (g stride 8192 elem)
__global__ __launch_bounds__(256) void norm_kernel(
    const float* __restrict__ img, const float* __restrict__ gps,
    unsigned short* __restrict__ imgS, unsigned short* __restrict__ gpsS)
{
  int w    = (blockIdx.x * 256 + threadIdx.x) >> 6;  // one wave per row
  int lane = threadIdx.x & 63;

  f32x4 x = (f32x4){0.f, 0.f, 0.f, 0.f};
  bool isimg; int b = 0, n = 0, g = 0, m = 0;
  if (w < BB * MPAD) {
    isimg = true; b = w >> 6; n = w & 63;
    if (n < NIMG)
      x = *reinterpret_cast<const f32x4*>(img + ((size_t)b * NIMG + n) * DIM + lane * 4);
  } else {
    isimg = false; int t = w - BB * MPAD; g = t >> 5; m = t & 31;
    x = *reinterpret_cast<const f32x4*>(gps + (size_t)t * DIM + lane * 4);
  }

  float ss = x[0]*x[0] + x[1]*x[1] + x[2]*x[2] + x[3]*x[3];
  #pragma unroll
  for (int d = 1; d < 64; d <<= 1) ss += __shfl_xor(ss, d);
  float inv = (ss > 0.f) ? (1.0f / fmaxf(sqrtf(ss), 1e-12f)) : 0.f;

  // pack this lane's 4 bf16 (elems lane*4 .. lane*4+3) into two u32
  unsigned int w01 = (unsigned)f2bf(x[0]*inv) | ((unsigned)f2bf(x[1]*inv) << 16);
  unsigned int w23 = (unsigned)f2bf(x[2]*inv) | ((unsigned)f2bf(x[3]*inv) << 16);

  // lane L (<32) gathers chunk L = row elems [8L, 8L+8) from lanes 2L, 2L+1
  int L = lane;
  unsigned int a0 = __shfl(w01, 2 * L);
  unsigned int a1 = __shfl(w23, 2 * L);
  unsigned int a2 = __shfl(w01, 2 * L + 1);
  unsigned int a3 = __shfl(w23, 2 * L + 1);
  if (L < 32) {
    u32x4 v = {a0, a1, a2, a3};
    unsigned short* dst;
    if (isimg) {
      dst = imgS + (size_t)b * 16384 + L * 512 + n * 8;          // [b][s=L][row n]
    } else {
      int mt = m >> 4, c = m & 15, kc = L >> 2, grp = L & 3;
      dst = gpsS + (size_t)g * 8192 + mt * 4096 + kc * 512 + (grp * 16 + c) * 8;
    }
    *reinterpret_cast<u32x4*>(dst) = v;
  }
}

// ---------------- kernel 2: all-pairs MFMA + fused max/mean reductions --------------
// grid: 2048 blocks = 256 b * 8 g-chunks; 4 waves/block, 2 g's per wave step.
// A (img[b], 64x256 bf16 = 32KB) staged once in LDS in FRAGMENT-CONTIGUOUS layout
// As[kc][hf][lane][16B]: hot-loop ds_read_b128 = one base reg + compile-time
// immediate (kc*4096 + hf*1024). No XOR swizzle, no per-kc address VALU; lane
// stride 16B -> 2-way bank alias = free (m136).
// r13 post-mortem: VALU-limited (VALUBusy 51 > MfmaUtil 39, sum ~90%). r14 cuts:
//  (1) fragment-contiguous LDS (addressing VALU -> 0)
//  (2) peeled kc0 with shared zero C (kills 64 v_accvgpr_write per st)
//  (3) max3-shaped fmax trees (v_max3_f32)
// TRANSPOSED mfma: gps frag = A-operand, img frag = B-operand -> D = S^T.
// kc loop `#pragma unroll 2` liveness throttle (r7); (256,3) cap 170, no spill.
// Spill guard: WRITE_SIZE must stay ~0.5MB.
__global__ __launch_bounds__(256, 3) void pair_kernel(
    const unsigned short* __restrict__ imgS, const unsigned short* __restrict__ gpsS,
    float* __restrict__ i2g, float* __restrict__ g2i)
{
  int tid  = threadIdx.x;
  int wv   = tid >> 6;
  int lane = tid & 63;
  int c    = lane & 15;
  int b    = blockIdx.x >> 3, gc = blockIdx.x & 7;
  int wvu  = __builtin_amdgcn_readfirstlane(wv);   // wave-uniform -> SGPR

  __shared__ unsigned short As[8 * 4 * 64 * 8];    // [kc][hf][lane][8] = 32 KB

  // ---- stage A: global [b][s=kc*4+grp][n=hf*16+c] -> LDS [kc][hf][grp*16+c] ----
  // wave wvu handles hf = wvu; iteration i handles kc = i.
  {
    const unsigned short* src = imgS + (size_t)b * 16384;
    #pragma unroll
    for (int i = 0; i < 8; ++i) {
      bf16x8 v = *reinterpret_cast<const bf16x8*>(
          src + (i * 4 + (lane >> 4)) * 512 + (wvu * 16 + (lane & 15)) * 8);
      *reinterpret_cast<bf16x8*>(
          reinterpret_cast<char*>(As) + i * 4096 + wvu * 1024 + lane * 16) = v;
    }
  }
  __syncthreads();

  const char* ab = reinterpret_cast<const char*>(As) + lane * 16;

  // wave-uniform gps tile base (SGPR) + single per-lane element offset
  const unsigned short* gb = gpsS + ((size_t)(gc * 32 + wvu * 8)) * 8192;
  unsigned int lane8 = lane * 8;

  #pragma unroll 1
  for (int st = 0; st < 4; ++st) {
    f32x4 acc[2][2][4];                        // [g][mt (gps rows)][hf (img cols)]

    // ---- peeled kc = 0: C = shared zero vector (no per-acc zero-init) ----
    {
      const unsigned short* p = gb + lane8;
      bf16x8 q00 = *reinterpret_cast<const bf16x8*>(p);
      bf16x8 q01 = *reinterpret_cast<const bf16x8*>(p + 4096);
      bf16x8 q10 = *reinterpret_cast<const bf16x8*>(p + 8192);
      bf16x8 q11 = *reinterpret_cast<const bf16x8*>(p + 12288);
      bf16x8 a0 = *reinterpret_cast<const bf16x8*>(ab);
      bf16x8 a1 = *reinterpret_cast<const bf16x8*>(ab + 1024);
      bf16x8 a2 = *reinterpret_cast<const bf16x8*>(ab + 2048);
      bf16x8 a3 = *reinterpret_cast<const bf16x8*>(ab + 3072);
      const f32x4 Z = {0.f, 0.f, 0.f, 0.f};
      acc[0][0][0] = __builtin_amdgcn_mfma_f32_16x16x32_bf16(q00, a0, Z, 0, 0, 0);
      acc[0][0][1] = __builtin_amdgcn_mfma_f32_16x16x32_bf16(q00, a1, Z, 0, 0, 0);
      acc[0][0][2] = __builtin_amdgcn_mfma_f32_16x16x32_bf16(q00, a2, Z, 0, 0, 0);
      acc[0][0][3] = __builtin_amdgcn_mfma_f32_16x16x32_bf16(q00, a3, Z, 0, 0, 0);
      acc[0][1][0] = __builtin_amdgcn_mfma_f32_16x16x32_bf16(q01, a0, Z, 0, 0, 0);
      acc[0][1][1] = __builtin_amdgcn_mfma_f32_16x16x32_bf16(q01, a1, Z, 0, 0, 0);
      acc[0][1][2] = __builtin_amdgcn_mfma_f32_16x16x32_bf16(q01, a2, Z, 0, 0, 0);
      acc[0][1][3] = __builtin_amdgcn_mfma_f32_16x16x32_bf16(q01, a3, Z, 0, 0, 0);
      acc[1][0][0] = __builtin_amdgcn_mfma_f32_16x16x32_bf16(q10, a0, Z, 0, 0, 0);
      acc[1][0][1] = __builtin_amdgcn_mfma_f32_16x16x32_bf16(q10, a1, Z, 0, 0, 0);
      acc[1][0][2] = __builtin_amdgcn_mfma_f32_16x16x32_bf16(q10, a2, Z, 0, 0, 0);
      acc[1][0][3] = __builtin_amdgcn_mfma_f32_16x16x32_bf16(q10, a3, Z, 0, 0, 0);
      acc[1][1][0] = __builtin_amdgcn_mfma_f32_16x16x32_bf16(q11, a0, Z, 0, 0, 0);
      acc[1][1][1] = __builtin_amdgcn_mfma_f32_16x16x32_bf16(q11, a1, Z, 0, 0, 0);
      acc[1][1][2] = __builtin_amdgcn_mfma_f32_16x16x32_bf16(q11, a2, Z, 0, 0, 0);
      acc[1][1][3] = __builtin_amdgcn_mfma_f32_16x16x32_bf16(q11, a3, Z, 0, 0, 0);
    }

    #pragma unroll 2
    for (int kc = 1; kc < 8; ++kc) {
      const unsigned short* p = gb + kc * 512 + lane8;
      bf16x8 q00 = *reinterpret_cast<const bf16x8*>(p);
      bf16x8 q01 = *reinterpret_cast<const bf16x8*>(p + 4096);
      bf16x8 q10 = *reinterpret_cast<const bf16x8*>(p + 8192);
      bf16x8 q11 = *reinterpret_cast<const bf16x8*>(p + 12288);
      const char* ak = ab + kc * 4096;
      bf16x8 a0 = *reinterpret_cast<const bf16x8*>(ak);
      bf16x8 a1 = *reinterpret_cast<const bf16x8*>(ak + 1024);
      bf16x8 a2 = *reinterpret_cast<const bf16x8*>(ak + 2048);
      bf16x8 a3 = *reinterpret_cast<const bf16x8*>(ak + 3072);
      acc[0][0][0] = __builtin_amdgcn_mfma_f32_16x16x32_bf16(q00, a0, acc[0][0][0], 0, 0, 0);
      acc[0][0][1] = __builtin_amdgcn_mfma_f32_16x16x32_bf16(q00, a1, acc[0][0][1], 0, 0, 0);
      acc[0][0][2] = __builtin_amdgcn_mfma_f32_16x16x32_bf16(q00, a2, acc[0][0][2], 0, 0, 0);
      acc[0][0][3] = __builtin_amdgcn_mfma_f32_16x16x32_bf16(q00, a3, acc[0][0][3], 0, 0, 0);
      acc[0][1][0] = __builtin_amdgcn_mfma_f32_16x16x32_bf16(q01, a0, acc[0][1][0], 0, 0, 0);
      acc[0][1][1] = __builtin_amdgcn_mfma_f32_16x16x32_bf16(q01, a1, acc[0][1][1], 0, 0, 0);
      acc[0][1][2] = __builtin_amdgcn_mfma_f32_16x16x32_bf16(q01, a2, acc[0][1][2], 0, 0, 0);
      acc[0][1][3] = __builtin_amdgcn_mfma_f32_16x16x32_bf16(q01, a3, acc[0][1][3], 0, 0, 0);
      acc[1][0][0] = __builtin_amdgcn_mfma_f32_16x16x32_bf16(q10, a0, acc[1][0][0], 0, 0, 0);
      acc[1][0][1] = __builtin_amdgcn_mfma_f32_16x16x32_bf16(q10, a1, acc[1][0][1], 0, 0, 0);
      acc[1][0][2] = __builtin_amdgcn_mfma_f32_16x16x32_bf16(q10, a2, acc[1][0][2], 0, 0, 0);
      acc[1][0][3] = __builtin_amdgcn_mfma_f32_16x16x32_bf16(q10, a3, acc[1][0][3], 0, 0, 0);
      acc[1][1][0] = __builtin_amdgcn_mfma_f32_16x16x32_bf16(q11, a0, acc[1][1][0], 0, 0, 0);
      acc[1][1][1] = __builtin_amdgcn_mfma_f32_16x16x32_bf16(q11, a1, acc[1][1][1], 0, 0, 0);
      acc[1][1][2] = __builtin_amdgcn_mfma_f32_16x16x32_bf16(q11, a2, acc[1][1][2], 0, 0, 0);
      acc[1][1][3] = __builtin_amdgcn_mfma_f32_16x16x32_bf16(q11, a3, acc[1][1][3], 0, 0, 0);
    }

    // ---- epilogue per g: D = S^T, row m = mt*16+grp*4+r (gps), col n = hf*16+c ----
    #pragma unroll
    for (int g = 0; g < 2; ++g) {
      // i2g: mean over n<49 of (max over m). max over m: in-lane (mt,r) + xor16/32.
      float vmax[4];
      #pragma unroll
      for (int hf = 0; hf < 4; ++hf) {
        float vm = fmaxf(max3f(acc[g][0][hf][0], acc[g][0][hf][1], acc[g][0][hf][2]),
                         max3f(acc[g][0][hf][3], acc[g][1][hf][0], acc[g][1][hf][1]));
        vm = max3f(vm, acc[g][1][hf][2], acc[g][1][hf][3]);
        vm = fmaxf(vm, __shfl_xor(vm, 16));
        vm = fmaxf(vm, __shfl_xor(vm, 32));
        vmax[hf] = vm;
      }
      // valid n: hf<3 all 16 c's; hf==3 only c==0 (n=48)
      float s = max3f(0.f, 0.f, 0.f);          // dummy to keep shape; replaced below
      s = vmax[0] + vmax[1] + vmax[2] + ((c == 0) ? vmax[3] : 0.0f);
      s = sum16(s);                            // sum over c -> sum over n<49

      // g2i: mean over 32 m of (max over n<49). in-lane over hf (mask hf3), max16
      // over c, then sum over (mt,r) in-lane + xor16/32 over grp.
      float t = 0.f;
      #pragma unroll
      for (int mt = 0; mt < 2; ++mt)
        #pragma unroll
        for (int r = 0; r < 4; ++r) {
          float h3 = (c == 0) ? acc[g][mt][3][r] : -3.0e38f;
          float hm = fmaxf(max3f(acc[g][mt][0][r], acc[g][mt][1][r], acc[g][mt][2][r]), h3);
          hm = max16(hm);
          t += hm;
        }
      t += __shfl_xor(t, 16);
      t += __shfl_xor(t, 32);

      if (lane == 0) {
        int gg = gc * 32 + wvu * 8 + st * 2 + g;
        i2g[b * 256 + gg] = s * (1.0f / NIMG);
        g2i[gg * 256 + b] = t * (1.0f / NGPS);
      }
    }
    gb += 16384;                               // advance 2 g tiles (2*8192 elems)
  }
}

// ---------------- kernel 3: per-row CE partials -------------------------------------
__global__ __launch_bounds__(256) void ce_kernel(
    const float* __restrict__ i2g, const float* __restrict__ g2i,
    const float* __restrict__ lsp, float* __restrict__ partial)
{
  int b = blockIdx.x, t = threadIdx.x, lane = t & 63, wv = t >> 6;
  float s = fminf(expf(lsp[0]), 100.0f);
  float v1 = s * i2g[b * 256 + t];
  float v2 = s * g2i[b * 256 + t];

  float m1 = v1, m2 = v2;
  #pragma unroll
  for (int d = 1; d < 64; d <<= 1) {
    m1 = fmaxf(m1, __shfl_xor(m1, d));
    m2 = fmaxf(m2, __shfl_xor(m2, d));
  }
  __shared__ float sm[2][4];
  if (lane == 0) { sm[0][wv] = m1; sm[1][wv] = m2; }
  __syncthreads();
  m1 = fmaxf(fmaxf(sm[0][0], sm[0][1]), fmaxf(sm[0][2], sm[0][3]));
  m2 = fmaxf(fmaxf(sm[1][0], sm[1][1]), fmaxf(sm[1][2], sm[1][3]));

  float e1 = expf(v1 - m1), e2 = expf(v2 - m2);
  #pragma unroll
  for (int d = 1; d < 64; d <<= 1) {
    e1 += __shfl_xor(e1, d);
    e2 += __shfl_xor(e2, d);
  }
  __shared__ float se[2][4];
  if (lane == 0) { se[0][wv] = e1; se[1][wv] = e2; }
  __syncthreads();
  if (t == 0) {
    float S1 = se[0][0] + se[0][1] + se[0][2] + se[0][3];
    float S2 = se[1][0] + se[1][1] + se[1][2] + se[1][3];
    float lse1 = m1 + logf(S1);
    float lse2 = m2 + logf(S2);
    partial[b] = (lse1 - s * i2g[b * 257]) + (lse2 - s * g2i[b * 257]);
  }
}

// ---------------- kernel 4: final scalar --------------------------------------------
__global__ __launch_bounds__(256) void finish_kernel(
    const float* __restrict__ partial, float* __restrict__ out)
{
  int t = threadIdx.x, lane = t & 63, wv = t >> 6;
  float v = partial[t];
  #pragma unroll
  for (int d = 1; d < 64; d <<= 1) v += __shfl_xor(v, d);
  __shared__ float sp[4];
  if (lane == 0) sp[wv] = v;
  __syncthreads();
  if (t == 0) out[0] = (sp[0] + sp[1] + sp[2] + sp[3]) * (1.0f / 512.0f);
}

extern "C" void kernel_launch(void* const* d_in, const int* in_sizes, int n_in,
                              void* d_out, int out_size, void* d_ws, size_t ws_size,
                              hipStream_t stream)
{
  const float* img = (const float*)d_in[0];
  const float* gps = (const float*)d_in[1];
  const float* lsp = (const float*)d_in[2];
  float* out = (float*)d_out;
  char* ws = (char*)d_ws;

  unsigned short* imgS = (unsigned short*)(ws);              //  8,388,608 B
  unsigned short* gpsS = (unsigned short*)(ws + 8388608);    //  4,194,304 B
  float* i2g     = (float*)(ws + 12582912);                  //    262,144 B
  float* g2i     = (float*)(ws + 12845056);                  //    262,144 B
  float* partial = (float*)(ws + 13107200);                  //      1,024 B

  norm_kernel<<<6144, 256, 0, stream>>>(img, gps, imgS, gpsS);
  pair_kernel<<<2048, 256, 0, stream>>>(imgS, gpsS, i2g, g2i);
  ce_kernel<<<256, 256, 0, stream>>>(i2g, g2i, lsp, partial);
  finish_kernel<<<1, 256, 0, stream>>>(partial, out);
}

// Round 16
// 84.922 us; speedup vs baseline: 2.3130x; 2.3130x over previous
//
#include <hip/hip_runtime.h>

#define BB   256
#define NIMG 49
#define NGPS 32
#define DIM  256
#define MPAD 64

typedef __attribute__((ext_vector_type(8))) __bf16 bf16x8;
typedef __attribute__((ext_vector_type(4))) float  f32x4;
typedef __attribute__((ext_vector_type(4))) unsigned int u32x4;

__device__ inline unsigned short f2bf(float f) {
  unsigned int u = __float_as_uint(f);
  u += 0x7fff + ((u >> 16) & 1);   // round-to-nearest-even
  return (unsigned short)(u >> 16);
}

__device__ inline float max3f(float a, float b, float c) {
  return fmaxf(fmaxf(a, b), c);    // clang folds to v_max3_f32
}

// DPP cross-lane reduce helpers (VALU pipe, no DS traffic).
template<int CTRL>
__device__ inline float dppmax(float v) {
  float o = __int_as_float(__builtin_amdgcn_update_dpp(0, __float_as_int(v), CTRL, 0xF, 0xF, true));
  return fmaxf(v, o);
}
template<int CTRL>
__device__ inline float dppadd(float v) {
  float o = __int_as_float(__builtin_amdgcn_update_dpp(0, __float_as_int(v), CTRL, 0xF, 0xF, true));
  return v + o;
}
__device__ inline float max16(float v) {   // max across the 16 lanes of a DPP row
  v = dppmax<0xB1>(v); v = dppmax<0x4E>(v); v = dppmax<0x141>(v); v = dppmax<0x140>(v);
  return v;
}
__device__ inline float sum16(float v) {   // sum across the 16 lanes of a DPP row
  v = dppadd<0xB1>(v); v = dppadd<0x4E>(v); v = dppadd<0x141>(v); v = dppadd<0x140>(v);
  return v;
}

// ---------------- kernel 1: L2-normalize + cast to bf16, FRAGMENT-CONTIGUOUS layout --
// (r9 win: +44%. Every hot-loop global load is `lane i reads base + i*16B`.)
//   imgS[b][chunk s=0..31][row 0..63][8 bf16]  (b stride 16384 elem)
//   gpsS[g][mt][kc][grp*16+c][8 bf16]          (g stride 8192 elem)
__global__ __launch_bounds__(256) void norm_kernel(
    const float* __restrict__ img, const float* __restrict__ gps,
    unsigned short* __restrict__ imgS, unsigned short* __restrict__ gpsS)
{
  int w    = (blockIdx.x * 256 + threadIdx.x) >> 6;  // one wave per row
  int lane = threadIdx.x & 63;

  f32x4 x = (f32x4){0.f, 0.f, 0.f, 0.f};
  bool isimg; int b = 0, n = 0, g = 0, m = 0;
  if (w < BB * MPAD) {
    isimg = true; b = w >> 6; n = w & 63;
    if (n < NIMG)
      x = *reinterpret_cast<const f32x4*>(img + ((size_t)b * NIMG + n) * DIM + lane * 4);
  } else {
    isimg = false; int t = w - BB * MPAD; g = t >> 5; m = t & 31;
    x = *reinterpret_cast<const f32x4*>(gps + (size_t)t * DIM + lane * 4);
  }

  float ss = x[0]*x[0] + x[1]*x[1] + x[2]*x[2] + x[3]*x[3];
  #pragma unroll
  for (int d = 1; d < 64; d <<= 1) ss += __shfl_xor(ss, d);
  float inv = (ss > 0.f) ? (1.0f / fmaxf(sqrtf(ss), 1e-12f)) : 0.f;

  // pack this lane's 4 bf16 (elems lane*4 .. lane*4+3) into two u32
  unsigned int w01 = (unsigned)f2bf(x[0]*inv) | ((unsigned)f2bf(x[1]*inv) << 16);
  unsigned int w23 = (unsigned)f2bf(x[2]*inv) | ((unsigned)f2bf(x[3]*inv) << 16);

  // lane L (<32) gathers chunk L = row elems [8L, 8L+8) from lanes 2L, 2L+1
  int L = lane;
  unsigned int a0 = __shfl(w01, 2 * L);
  unsigned int a1 = __shfl(w23, 2 * L);
  unsigned int a2 = __shfl(w01, 2 * L + 1);
  unsigned int a3 = __shfl(w23, 2 * L + 1);
  if (L < 32) {
    u32x4 v = {a0, a1, a2, a3};
    unsigned short* dst;
    if (isimg) {
      dst = imgS + (size_t)b * 16384 + L * 512 + n * 8;          // [b][s=L][row n]
    } else {
      int mt = m >> 4, c = m & 15, kc = L >> 2, grp = L & 3;
      dst = gpsS + (size_t)g * 8192 + mt * 4096 + kc * 512 + (grp * 16 + c) * 8;
    }
    *reinterpret_cast<u32x4*>(dst) = v;
  }
}

// ---------------- kernel 2: all-pairs MFMA + fused max/mean reductions --------------
// grid: 2048 blocks = 256 b * 8 g-chunks; 4 waves/block, 2 g's per wave step.
// A (img[b], 64x256 bf16 = 32KB) staged once in LDS in FRAGMENT-CONTIGUOUS layout
// As[kc][hf][lane][16B]: hot-loop ds_read_b128 = base reg + offset. Bank
// conflicts = 0 (verified r14), zero addressing VALU.
// r14 post-mortem: cheap addressing removed the natural liveness throttle --
// with `unroll 2` the scheduler hoisted 2 iterations' 16 loads past the cap ->
// 140MB spill. r15: kc loop is `#pragma unroll 1` (8 loads in flight + acc 64
// ~= 130-140 combined, fits (256,3)'s 170 cap). DO NOT raise the unroll.
// Peeled kc0 with shared zero C (no 64x v_accvgpr_write); max3 fmax trees.
// TRANSPOSED mfma: gps frag = A-operand, img frag = B-operand -> D = S^T.
// Spill guard: WRITE_SIZE must stay ~0.5MB.
__global__ __launch_bounds__(256, 3) void pair_kernel(
    const unsigned short* __restrict__ imgS, const unsigned short* __restrict__ gpsS,
    float* __restrict__ i2g, float* __restrict__ g2i)
{
  int tid  = threadIdx.x;
  int wv   = tid >> 6;
  int lane = tid & 63;
  int c    = lane & 15;
  int b    = blockIdx.x >> 3, gc = blockIdx.x & 7;
  int wvu  = __builtin_amdgcn_readfirstlane(wv);   // wave-uniform -> SGPR

  __shared__ unsigned short As[8 * 4 * 64 * 8];    // [kc][hf][lane][8] = 32 KB

  // ---- stage A: global [b][s=kc*4+grp][n=hf*16+c] -> LDS [kc][hf][grp*16+c] ----
  // wave wvu handles hf = wvu; iteration i handles kc = i.
  {
    const unsigned short* src = imgS + (size_t)b * 16384;
    #pragma unroll
    for (int i = 0; i < 8; ++i) {
      bf16x8 v = *reinterpret_cast<const bf16x8*>(
          src + (i * 4 + (lane >> 4)) * 512 + (wvu * 16 + (lane & 15)) * 8);
      *reinterpret_cast<bf16x8*>(
          reinterpret_cast<char*>(As) + i * 4096 + wvu * 1024 + lane * 16) = v;
    }
  }
  __syncthreads();

  const char* ab = reinterpret_cast<const char*>(As) + lane * 16;

  // wave-uniform gps tile base (SGPR) + single per-lane element offset
  const unsigned short* gb = gpsS + ((size_t)(gc * 32 + wvu * 8)) * 8192;
  unsigned int lane8 = lane * 8;

  #pragma unroll 1
  for (int st = 0; st < 4; ++st) {
    f32x4 acc[2][2][4];                        // [g][mt (gps rows)][hf (img cols)]

    // ---- peeled kc = 0: C = shared zero vector (no per-acc zero-init) ----
    {
      const unsigned short* p = gb + lane8;
      bf16x8 q00 = *reinterpret_cast<const bf16x8*>(p);
      bf16x8 q01 = *reinterpret_cast<const bf16x8*>(p + 4096);
      bf16x8 q10 = *reinterpret_cast<const bf16x8*>(p + 8192);
      bf16x8 q11 = *reinterpret_cast<const bf16x8*>(p + 12288);
      bf16x8 a0 = *reinterpret_cast<const bf16x8*>(ab);
      bf16x8 a1 = *reinterpret_cast<const bf16x8*>(ab + 1024);
      bf16x8 a2 = *reinterpret_cast<const bf16x8*>(ab + 2048);
      bf16x8 a3 = *reinterpret_cast<const bf16x8*>(ab + 3072);
      const f32x4 Z = {0.f, 0.f, 0.f, 0.f};
      acc[0][0][0] = __builtin_amdgcn_mfma_f32_16x16x32_bf16(q00, a0, Z, 0, 0, 0);
      acc[0][0][1] = __builtin_amdgcn_mfma_f32_16x16x32_bf16(q00, a1, Z, 0, 0, 0);
      acc[0][0][2] = __builtin_amdgcn_mfma_f32_16x16x32_bf16(q00, a2, Z, 0, 0, 0);
      acc[0][0][3] = __builtin_amdgcn_mfma_f32_16x16x32_bf16(q00, a3, Z, 0, 0, 0);
      acc[0][1][0] = __builtin_amdgcn_mfma_f32_16x16x32_bf16(q01, a0, Z, 0, 0, 0);
      acc[0][1][1] = __builtin_amdgcn_mfma_f32_16x16x32_bf16(q01, a1, Z, 0, 0, 0);
      acc[0][1][2] = __builtin_amdgcn_mfma_f32_16x16x32_bf16(q01, a2, Z, 0, 0, 0);
      acc[0][1][3] = __builtin_amdgcn_mfma_f32_16x16x32_bf16(q01, a3, Z, 0, 0, 0);
      acc[1][0][0] = __builtin_amdgcn_mfma_f32_16x16x32_bf16(q10, a0, Z, 0, 0, 0);
      acc[1][0][1] = __builtin_amdgcn_mfma_f32_16x16x32_bf16(q10, a1, Z, 0, 0, 0);
      acc[1][0][2] = __builtin_amdgcn_mfma_f32_16x16x32_bf16(q10, a2, Z, 0, 0, 0);
      acc[1][0][3] = __builtin_amdgcn_mfma_f32_16x16x32_bf16(q10, a3, Z, 0, 0, 0);
      acc[1][1][0] = __builtin_amdgcn_mfma_f32_16x16x32_bf16(q11, a0, Z, 0, 0, 0);
      acc[1][1][1] = __builtin_amdgcn_mfma_f32_16x16x32_bf16(q11, a1, Z, 0, 0, 0);
      acc[1][1][2] = __builtin_amdgcn_mfma_f32_16x16x32_bf16(q11, a2, Z, 0, 0, 0);
      acc[1][1][3] = __builtin_amdgcn_mfma_f32_16x16x32_bf16(q11, a3, Z, 0, 0, 0);
    }

    #pragma unroll 1
    for (int kc = 1; kc < 8; ++kc) {
      const unsigned short* p = gb + kc * 512 + lane8;
      bf16x8 q00 = *reinterpret_cast<const bf16x8*>(p);
      bf16x8 q01 = *reinterpret_cast<const bf16x8*>(p + 4096);
      bf16x8 q10 = *reinterpret_cast<const bf16x8*>(p + 8192);
      bf16x8 q11 = *reinterpret_cast<const bf16x8*>(p + 12288);
      const char* ak = ab + kc * 4096;
      bf16x8 a0 = *reinterpret_cast<const bf16x8*>(ak);
      bf16x8 a1 = *reinterpret_cast<const bf16x8*>(ak + 1024);
      bf16x8 a2 = *reinterpret_cast<const bf16x8*>(ak + 2048);
      bf16x8 a3 = *reinterpret_cast<const bf16x8*>(ak + 3072);
      acc[0][0][0] = __builtin_amdgcn_mfma_f32_16x16x32_bf16(q00, a0, acc[0][0][0], 0, 0, 0);
      acc[0][0][1] = __builtin_amdgcn_mfma_f32_16x16x32_bf16(q00, a1, acc[0][0][1], 0, 0, 0);
      acc[0][0][2] = __builtin_amdgcn_mfma_f32_16x16x32_bf16(q00, a2, acc[0][0][2], 0, 0, 0);
      acc[0][0][3] = __builtin_amdgcn_mfma_f32_16x16x32_bf16(q00, a3, acc[0][0][3], 0, 0, 0);
      acc[0][1][0] = __builtin_amdgcn_mfma_f32_16x16x32_bf16(q01, a0, acc[0][1][0], 0, 0, 0);
      acc[0][1][1] = __builtin_amdgcn_mfma_f32_16x16x32_bf16(q01, a1, acc[0][1][1], 0, 0, 0);
      acc[0][1][2] = __builtin_amdgcn_mfma_f32_16x16x32_bf16(q01, a2, acc[0][1][2], 0, 0, 0);
      acc[0][1][3] = __builtin_amdgcn_mfma_f32_16x16x32_bf16(q01, a3, acc[0][1][3], 0, 0, 0);
      acc[1][0][0] = __builtin_amdgcn_mfma_f32_16x16x32_bf16(q10, a0, acc[1][0][0], 0, 0, 0);
      acc[1][0][1] = __builtin_amdgcn_mfma_f32_16x16x32_bf16(q10, a1, acc[1][0][1], 0, 0, 0);
      acc[1][0][2] = __builtin_amdgcn_mfma_f32_16x16x32_bf16(q10, a2, acc[1][0][2], 0, 0, 0);
      acc[1][0][3] = __builtin_amdgcn_mfma_f32_16x16x32_bf16(q10, a3, acc[1][0][3], 0, 0, 0);
      acc[1][1][0] = __builtin_amdgcn_mfma_f32_16x16x32_bf16(q11, a0, acc[1][1][0], 0, 0, 0);
      acc[1][1][1] = __builtin_amdgcn_mfma_f32_16x16x32_bf16(q11, a1, acc[1][1][1], 0, 0, 0);
      acc[1][1][2] = __builtin_amdgcn_mfma_f32_16x16x32_bf16(q11, a2, acc[1][1][2], 0, 0, 0);
      acc[1][1][3] = __builtin_amdgcn_mfma_f32_16x16x32_bf16(q11, a3, acc[1][1][3], 0, 0, 0);
    }

    // ---- epilogue per g: D = S^T, row m = mt*16+grp*4+r (gps), col n = hf*16+c ----
    #pragma unroll
    for (int g = 0; g < 2; ++g) {
      // i2g: mean over n<49 of (max over m). max over m: in-lane (mt,r) + xor16/32.
      float vmax[4];
      #pragma unroll
      for (int hf = 0; hf < 4; ++hf) {
        float vm = fmaxf(max3f(acc[g][0][hf][0], acc[g][0][hf][1], acc[g][0][hf][2]),
                         max3f(acc[g][0][hf][3], acc[g][1][hf][0], acc[g][1][hf][1]));
        vm = max3f(vm, acc[g][1][hf][2], acc[g][1][hf][3]);
        vm = fmaxf(vm, __shfl_xor(vm, 16));
        vm = fmaxf(vm, __shfl_xor(vm, 32));
        vmax[hf] = vm;
      }
      // valid n: hf<3 all 16 c's; hf==3 only c==0 (n=48)
      float s = vmax[0] + vmax[1] + vmax[2] + ((c == 0) ? vmax[3] : 0.0f);
      s = sum16(s);                            // sum over c -> sum over n<49

      // g2i: mean over 32 m of (max over n<49). in-lane over hf (mask hf3), max16
      // over c, then sum over (mt,r) in-lane + xor16/32 over grp.
      float t = 0.f;
      #pragma unroll
      for (int mt = 0; mt < 2; ++mt)
        #pragma unroll
        for (int r = 0; r < 4; ++r) {
          float h3 = (c == 0) ? acc[g][mt][3][r] : -3.0e38f;
          float hm = fmaxf(max3f(acc[g][mt][0][r], acc[g][mt][1][r], acc[g][mt][2][r]), h3);
          hm = max16(hm);
          t += hm;
        }
      t += __shfl_xor(t, 16);
      t += __shfl_xor(t, 32);

      if (lane == 0) {
        int gg = gc * 32 + wvu * 8 + st * 2 + g;
        i2g[b * 256 + gg] = s * (1.0f / NIMG);
        g2i[gg * 256 + b] = t * (1.0f / NGPS);
      }
    }
    gb += 16384;                               // advance 2 g tiles (2*8192 elems)
  }
}

// ---------------- kernel 3: per-row CE partials -------------------------------------
__global__ __launch_bounds__(256) void ce_kernel(
    const float* __restrict__ i2g, const float* __restrict__ g2i,
    const float* __restrict__ lsp, float* __restrict__ partial)
{
  int b = blockIdx.x, t = threadIdx.x, lane = t & 63, wv = t >> 6;
  float s = fminf(expf(lsp[0]), 100.0f);
  float v1 = s * i2g[b * 256 + t];
  float v2 = s * g2i[b * 256 + t];

  float m1 = v1, m2 = v2;
  #pragma unroll
  for (int d = 1; d < 64; d <<= 1) {
    m1 = fmaxf(m1, __shfl_xor(m1, d));
    m2 = fmaxf(m2, __shfl_xor(m2, d));
  }
  __shared__ float sm[2][4];
  if (lane == 0) { sm[0][wv] = m1; sm[1][wv] = m2; }
  __syncthreads();
  m1 = fmaxf(fmaxf(sm[0][0], sm[0][1]), fmaxf(sm[0][2], sm[0][3]));
  m2 = fmaxf(fmaxf(sm[1][0], sm[1][1]), fmaxf(sm[1][2], sm[1][3]));

  float e1 = expf(v1 - m1), e2 = expf(v2 - m2);
  #pragma unroll
  for (int d = 1; d < 64; d <<= 1) {
    e1 += __shfl_xor(e1, d);
    e2 += __shfl_xor(e2, d);
  }
  __shared__ float se[2][4];
  if (lane == 0) { se[0][wv] = e1; se[1][wv] = e2; }
  __syncthreads();
  if (t == 0) {
    float S1 = se[0][0] + se[0][1] + se[0][2] + se[0][3];
    float S2 = se[1][0] + se[1][1] + se[1][2] + se[1][3];
    float lse1 = m1 + logf(S1);
    float lse2 = m2 + logf(S2);
    partial[b] = (lse1 - s * i2g[b * 257]) + (lse2 - s * g2i[b * 257]);
  }
}

// ---------------- kernel 4: final scalar --------------------------------------------
__global__ __launch_bounds__(256) void finish_kernel(
    const float* __restrict__ partial, float* __restrict__ out)
{
  int t = threadIdx.x, lane = t & 63, wv = t >> 6;
  float v = partial[t];
  #pragma unroll
  for (int d = 1; d < 64; d <<= 1) v += __shfl_xor(v, d);
  __shared__ float sp[4];
  if (lane == 0) sp[wv] = v;
  __syncthreads();
  if (t == 0) out[0] = (sp[0] + sp[1] + sp[2] + sp[3]) * (1.0f / 512.0f);
}

extern "C" void kernel_launch(void* const* d_in, const int* in_sizes, int n_in,
                              void* d_out, int out_size, void* d_ws, size_t ws_size,
                              hipStream_t stream)
{
  const float* img = (const float*)d_in[0];
  const float* gps = (const float*)d_in[1];
  const float* lsp = (const float*)d_in[2];
  float* out = (float*)d_out;
  char* ws = (char*)d_ws;

  unsigned short* imgS = (unsigned short*)(ws);              //  8,388,608 B
  unsigned short* gpsS = (unsigned short*)(ws + 8388608);    //  4,194,304 B
  float* i2g     = (float*)(ws + 12582912);                  //    262,144 B
  float* g2i     = (float*)(ws + 12845056);                  //    262,144 B
  float* partial = (float*)(ws + 13107200);                  //      1,024 B

  norm_kernel<<<6144, 256, 0, stream>>>(img, gps, imgS, gpsS);
  pair_kernel<<<2048, 256, 0, stream>>>(imgS, gpsS, i2g, g2i);
  ce_kernel<<<256, 256, 0, stream>>>(i2g, g2i, lsp, partial);
  finish_kernel<<<1, 256, 0, stream>>>(partial, out);
}

// Round 19
// 84.423 us; speedup vs baseline: 2.3266x; 1.0059x over previous
//
#include <hip/hip_runtime.h>

#define BB   256
#define NIMG 49
#define NGPS 32
#define DIM  256
#define MPAD 64

typedef __attribute__((ext_vector_type(8))) __bf16 bf16x8;
typedef __attribute__((ext_vector_type(4))) float  f32x4;
typedef __attribute__((ext_vector_type(4))) unsigned int u32x4;

__device__ inline unsigned short f2bf(float f) {
  unsigned int u = __float_as_uint(f);
  u += 0x7fff + ((u >> 16) & 1);   // round-to-nearest-even
  return (unsigned short)(u >> 16);
}

__device__ inline float max3f(float a, float b, float c) {
  return fmaxf(fmaxf(a, b), c);    // clang folds to v_max3_f32
}

// DPP cross-lane reduce helpers (VALU pipe, no DS traffic).
template<int CTRL>
__device__ inline float dppmax(float v) {
  float o = __int_as_float(__builtin_amdgcn_update_dpp(0, __float_as_int(v), CTRL, 0xF, 0xF, true));
  return fmaxf(v, o);
}
template<int CTRL>
__device__ inline float dppadd(float v) {
  float o = __int_as_float(__builtin_amdgcn_update_dpp(0, __float_as_int(v), CTRL, 0xF, 0xF, true));
  return v + o;
}
__device__ inline float max16(float v) {   // max across the 16 lanes of a DPP row
  v = dppmax<0xB1>(v); v = dppmax<0x4E>(v); v = dppmax<0x141>(v); v = dppmax<0x140>(v);
  return v;
}
__device__ inline float sum16(float v) {   // sum across the 16 lanes of a DPP row
  v = dppadd<0xB1>(v); v = dppadd<0x4E>(v); v = dppadd<0x141>(v); v = dppadd<0x140>(v);
  return v;
}

// ---------------- kernel 1: L2-normalize + cast to bf16, FRAGMENT-CONTIGUOUS layout --
// (r9 win: +44%. Every hot-loop global load is `lane i reads base + i*16B`.)
//   imgS[b][chunk s=0..31][row 0..63][8 bf16]  (b stride 16384 elem)
//   gpsS[g][mt][kc][grp*16+c][8 bf16]          (g stride 8192 elem)
__global__ __launch_bounds__(256) void norm_kernel(
    const float* __restrict__ img, const float* __restrict__ gps,
    unsigned short* __restrict__ imgS, unsigned short* __restrict__ gpsS)
{
  int w    = (blockIdx.x * 256 + threadIdx.x) >> 6;  // one wave per row
  int lane = threadIdx.x & 63;

  f32x4 x = (f32x4){0.f, 0.f, 0.f, 0.f};
  bool isimg; int b = 0, n = 0, g = 0, m = 0;
  if (w < BB * MPAD) {
    isimg = true; b = w >> 6; n = w & 63;
    if (n < NIMG)
      x = *reinterpret_cast<const f32x4*>(img + ((size_t)b * NIMG + n) * DIM + lane * 4);
  } else {
    isimg = false; int t = w - BB * MPAD; g = t >> 5; m = t & 31;
    x = *reinterpret_cast<const f32x4*>(gps + (size_t)t * DIM + lane * 4);
  }

  float ss = x[0]*x[0] + x[1]*x[1] + x[2]*x[2] + x[3]*x[3];
  #pragma unroll
  for (int d = 1; d < 64; d <<= 1) ss += __shfl_xor(ss, d);
  float inv = (ss > 0.f) ? (1.0f / fmaxf(sqrtf(ss), 1e-12f)) : 0.f;

  // pack this lane's 4 bf16 (elems lane*4 .. lane*4+3) into two u32
  unsigned int w01 = (unsigned)f2bf(x[0]*inv) | ((unsigned)f2bf(x[1]*inv) << 16);
  unsigned int w23 = (unsigned)f2bf(x[2]*inv) | ((unsigned)f2bf(x[3]*inv) << 16);

  // lane L (<32) gathers chunk L = row elems [8L, 8L+8) from lanes 2L, 2L+1
  int L = lane;
  unsigned int a0 = __shfl(w01, 2 * L);
  unsigned int a1 = __shfl(w23, 2 * L);
  unsigned int a2 = __shfl(w01, 2 * L + 1);
  unsigned int a3 = __shfl(w23, 2 * L + 1);
  if (L < 32) {
    u32x4 v = {a0, a1, a2, a3};
    unsigned short* dst;
    if (isimg) {
      dst = imgS + (size_t)b * 16384 + L * 512 + n * 8;          // [b][s=L][row n]
    } else {
      int mt = m >> 4, c = m & 15, kc = L >> 2, grp = L & 3;
      dst = gpsS + (size_t)g * 8192 + mt * 4096 + kc * 512 + (grp * 16 + c) * 8;
    }
    *reinterpret_cast<u32x4*>(dst) = v;
  }
}

// ---------------- kernel 2: all-pairs MFMA + fused max/mean reductions --------------
// grid: 2048 blocks = 256 b * 8 g-chunks; 4 waves/block, 2 g's per wave step.
// A (img[b], 64x256 bf16 = 32KB) staged once in LDS in FRAGMENT-CONTIGUOUS layout
// As[kc][hf][lane][16B]: hot-loop ds_read_b128 = base reg + offset. Bank
// conflicts = 0 (verified r14/r16), zero addressing VALU.
// r16 post-mortem: MfmaUtil 39 + VALUBusy 45, pair 76us = m97-class plateau.
// Binding constraint is load-latency at 16-MFMA burst depth: 3 waves x 78cyc
// barely covers ~200cyc L2 latency -> 40% feed equilibrium.
// r17 probe: DOUBLE the burst depth. kc `#pragma unroll 2` (32-MFMA bursts,
// next 16 loads in flight) + (256,2) cap 256 (r14's unroll-2 spilled at cap
// 170 wanting ~190; at 256 it fits, occupancy floor 2 waves/SIMD = 512/256).
// Pre-commit: win -> keep; null/regress -> revert to r16, declare plateau.
// Spill guard: WRITE_SIZE must stay ~0.5MB.
__global__ __launch_bounds__(256, 2) void pair_kernel(
    const unsigned short* __restrict__ imgS, const unsigned short* __restrict__ gpsS,
    float* __restrict__ i2g, float* __restrict__ g2i)
{
  int tid  = threadIdx.x;
  int wv   = tid >> 6;
  int lane = tid & 63;
  int c    = lane & 15;
  int b    = blockIdx.x >> 3, gc = blockIdx.x & 7;
  int wvu  = __builtin_amdgcn_readfirstlane(wv);   // wave-uniform -> SGPR

  __shared__ unsigned short As[8 * 4 * 64 * 8];    // [kc][hf][lane][8] = 32 KB

  // ---- stage A: global [b][s=kc*4+grp][n=hf*16+c] -> LDS [kc][hf][grp*16+c] ----
  // wave wvu handles hf = wvu; iteration i handles kc = i.
  {
    const unsigned short* src = imgS + (size_t)b * 16384;
    #pragma unroll
    for (int i = 0; i < 8; ++i) {
      bf16x8 v = *reinterpret_cast<const bf16x8*>(
          src + (i * 4 + (lane >> 4)) * 512 + (wvu * 16 + (lane & 15)) * 8);
      *reinterpret_cast<bf16x8*>(
          reinterpret_cast<char*>(As) + i * 4096 + wvu * 1024 + lane * 16) = v;
    }
  }
  __syncthreads();

  const char* ab = reinterpret_cast<const char*>(As) + lane * 16;

  // wave-uniform gps tile base (SGPR) + single per-lane element offset
  const unsigned short* gb = gpsS + ((size_t)(gc * 32 + wvu * 8)) * 8192;
  unsigned int lane8 = lane * 8;

  #pragma unroll 1
  for (int st = 0; st < 4; ++st) {
    f32x4 acc[2][2][4];                        // [g][mt (gps rows)][hf (img cols)]

    // ---- peeled kc = 0: C = shared zero vector (no per-acc zero-init) ----
    {
      const unsigned short* p = gb + lane8;
      bf16x8 q00 = *reinterpret_cast<const bf16x8*>(p);
      bf16x8 q01 = *reinterpret_cast<const bf16x8*>(p + 4096);
      bf16x8 q10 = *reinterpret_cast<const bf16x8*>(p + 8192);
      bf16x8 q11 = *reinterpret_cast<const bf16x8*>(p + 12288);
      bf16x8 a0 = *reinterpret_cast<const bf16x8*>(ab);
      bf16x8 a1 = *reinterpret_cast<const bf16x8*>(ab + 1024);
      bf16x8 a2 = *reinterpret_cast<const bf16x8*>(ab + 2048);
      bf16x8 a3 = *reinterpret_cast<const bf16x8*>(ab + 3072);
      const f32x4 Z = {0.f, 0.f, 0.f, 0.f};
      acc[0][0][0] = __builtin_amdgcn_mfma_f32_16x16x32_bf16(q00, a0, Z, 0, 0, 0);
      acc[0][0][1] = __builtin_amdgcn_mfma_f32_16x16x32_bf16(q00, a1, Z, 0, 0, 0);
      acc[0][0][2] = __builtin_amdgcn_mfma_f32_16x16x32_bf16(q00, a2, Z, 0, 0, 0);
      acc[0][0][3] = __builtin_amdgcn_mfma_f32_16x16x32_bf16(q00, a3, Z, 0, 0, 0);
      acc[0][1][0] = __builtin_amdgcn_mfma_f32_16x16x32_bf16(q01, a0, Z, 0, 0, 0);
      acc[0][1][1] = __builtin_amdgcn_mfma_f32_16x16x32_bf16(q01, a1, Z, 0, 0, 0);
      acc[0][1][2] = __builtin_amdgcn_mfma_f32_16x16x32_bf16(q01, a2, Z, 0, 0, 0);
      acc[0][1][3] = __builtin_amdgcn_mfma_f32_16x16x32_bf16(q01, a3, Z, 0, 0, 0);
      acc[1][0][0] = __builtin_amdgcn_mfma_f32_16x16x32_bf16(q10, a0, Z, 0, 0, 0);
      acc[1][0][1] = __builtin_amdgcn_mfma_f32_16x16x32_bf16(q10, a1, Z, 0, 0, 0);
      acc[1][0][2] = __builtin_amdgcn_mfma_f32_16x16x32_bf16(q10, a2, Z, 0, 0, 0);
      acc[1][0][3] = __builtin_amdgcn_mfma_f32_16x16x32_bf16(q10, a3, Z, 0, 0, 0);
      acc[1][1][0] = __builtin_amdgcn_mfma_f32_16x16x32_bf16(q11, a0, Z, 0, 0, 0);
      acc[1][1][1] = __builtin_amdgcn_mfma_f32_16x16x32_bf16(q11, a1, Z, 0, 0, 0);
      acc[1][1][2] = __builtin_amdgcn_mfma_f32_16x16x32_bf16(q11, a2, Z, 0, 0, 0);
      acc[1][1][3] = __builtin_amdgcn_mfma_f32_16x16x32_bf16(q11, a3, Z, 0, 0, 0);
    }

    #pragma unroll 2
    for (int kc = 1; kc < 8; ++kc) {
      const unsigned short* p = gb + kc * 512 + lane8;
      bf16x8 q00 = *reinterpret_cast<const bf16x8*>(p);
      bf16x8 q01 = *reinterpret_cast<const bf16x8*>(p + 4096);
      bf16x8 q10 = *reinterpret_cast<const bf16x8*>(p + 8192);
      bf16x8 q11 = *reinterpret_cast<const bf16x8*>(p + 12288);
      const char* ak = ab + kc * 4096;
      bf16x8 a0 = *reinterpret_cast<const bf16x8*>(ak);
      bf16x8 a1 = *reinterpret_cast<const bf16x8*>(ak + 1024);
      bf16x8 a2 = *reinterpret_cast<const bf16x8*>(ak + 2048);
      bf16x8 a3 = *reinterpret_cast<const bf16x8*>(ak + 3072);
      acc[0][0][0] = __builtin_amdgcn_mfma_f32_16x16x32_bf16(q00, a0, acc[0][0][0], 0, 0, 0);
      acc[0][0][1] = __builtin_amdgcn_mfma_f32_16x16x32_bf16(q00, a1, acc[0][0][1], 0, 0, 0);
      acc[0][0][2] = __builtin_amdgcn_mfma_f32_16x16x32_bf16(q00, a2, acc[0][0][2], 0, 0, 0);
      acc[0][0][3] = __builtin_amdgcn_mfma_f32_16x16x32_bf16(q00, a3, acc[0][0][3], 0, 0, 0);
      acc[0][1][0] = __builtin_amdgcn_mfma_f32_16x16x32_bf16(q01, a0, acc[0][1][0], 0, 0, 0);
      acc[0][1][1] = __builtin_amdgcn_mfma_f32_16x16x32_bf16(q01, a1, acc[0][1][1], 0, 0, 0);
      acc[0][1][2] = __builtin_amdgcn_mfma_f32_16x16x32_bf16(q01, a2, acc[0][1][2], 0, 0, 0);
      acc[0][1][3] = __builtin_amdgcn_mfma_f32_16x16x32_bf16(q01, a3, acc[0][1][3], 0, 0, 0);
      acc[1][0][0] = __builtin_amdgcn_mfma_f32_16x16x32_bf16(q10, a0, acc[1][0][0], 0, 0, 0);
      acc[1][0][1] = __builtin_amdgcn_mfma_f32_16x16x32_bf16(q10, a1, acc[1][0][1], 0, 0, 0);
      acc[1][0][2] = __builtin_amdgcn_mfma_f32_16x16x32_bf16(q10, a2, acc[1][0][2], 0, 0, 0);
      acc[1][0][3] = __builtin_amdgcn_mfma_f32_16x16x32_bf16(q10, a3, acc[1][0][3], 0, 0, 0);
      acc[1][1][0] = __builtin_amdgcn_mfma_f32_16x16x32_bf16(q11, a0, acc[1][1][0], 0, 0, 0);
      acc[1][1][1] = __builtin_amdgcn_mfma_f32_16x16x32_bf16(q11, a1, acc[1][1][1], 0, 0, 0);
      acc[1][1][2] = __builtin_amdgcn_mfma_f32_16x16x32_bf16(q11, a2, acc[1][1][2], 0, 0, 0);
      acc[1][1][3] = __builtin_amdgcn_mfma_f32_16x16x32_bf16(q11, a3, acc[1][1][3], 0, 0, 0);
    }

    // ---- epilogue per g: D = S^T, row m = mt*16+grp*4+r (gps), col n = hf*16+c ----
    #pragma unroll
    for (int g = 0; g < 2; ++g) {
      // i2g: mean over n<49 of (max over m). max over m: in-lane (mt,r) + xor16/32.
      float vmax[4];
      #pragma unroll
      for (int hf = 0; hf < 4; ++hf) {
        float vm = fmaxf(max3f(acc[g][0][hf][0], acc[g][0][hf][1], acc[g][0][hf][2]),
                         max3f(acc[g][0][hf][3], acc[g][1][hf][0], acc[g][1][hf][1]));
        vm = max3f(vm, acc[g][1][hf][2], acc[g][1][hf][3]);
        vm = fmaxf(vm, __shfl_xor(vm, 16));
        vm = fmaxf(vm, __shfl_xor(vm, 32));
        vmax[hf] = vm;
      }
      // valid n: hf<3 all 16 c's; hf==3 only c==0 (n=48)
      float s = vmax[0] + vmax[1] + vmax[2] + ((c == 0) ? vmax[3] : 0.0f);
      s = sum16(s);                            // sum over c -> sum over n<49

      // g2i: mean over 32 m of (max over n<49). in-lane over hf (mask hf3), max16
      // over c, then sum over (mt,r) in-lane + xor16/32 over grp.
      float t = 0.f;
      #pragma unroll
      for (int mt = 0; mt < 2; ++mt)
        #pragma unroll
        for (int r = 0; r < 4; ++r) {
          float h3 = (c == 0) ? acc[g][mt][3][r] : -3.0e38f;
          float hm = fmaxf(max3f(acc[g][mt][0][r], acc[g][mt][1][r], acc[g][mt][2][r]), h3);
          hm = max16(hm);
          t += hm;
        }
      t += __shfl_xor(t, 16);
      t += __shfl_xor(t, 32);

      if (lane == 0) {
        int gg = gc * 32 + wvu * 8 + st * 2 + g;
        i2g[b * 256 + gg] = s * (1.0f / NIMG);
        g2i[gg * 256 + b] = t * (1.0f / NGPS);
      }
    }
    gb += 16384;                               // advance 2 g tiles (2*8192 elems)
  }
}

// ---------------- kernel 3: per-row CE partials -------------------------------------
__global__ __launch_bounds__(256) void ce_kernel(
    const float* __restrict__ i2g, const float* __restrict__ g2i,
    const float* __restrict__ lsp, float* __restrict__ partial)
{
  int b = blockIdx.x, t = threadIdx.x, lane = t & 63, wv = t >> 6;
  float s = fminf(expf(lsp[0]), 100.0f);
  float v1 = s * i2g[b * 256 + t];
  float v2 = s * g2i[b * 256 + t];

  float m1 = v1, m2 = v2;
  #pragma unroll
  for (int d = 1; d < 64; d <<= 1) {
    m1 = fmaxf(m1, __shfl_xor(m1, d));
    m2 = fmaxf(m2, __shfl_xor(m2, d));
  }
  __shared__ float sm[2][4];
  if (lane == 0) { sm[0][wv] = m1; sm[1][wv] = m2; }
  __syncthreads();
  m1 = fmaxf(fmaxf(sm[0][0], sm[0][1]), fmaxf(sm[0][2], sm[0][3]));
  m2 = fmaxf(fmaxf(sm[1][0], sm[1][1]), fmaxf(sm[1][2], sm[1][3]));

  float e1 = expf(v1 - m1), e2 = expf(v2 - m2);
  #pragma unroll
  for (int d = 1; d < 64; d <<= 1) {
    e1 += __shfl_xor(e1, d);
    e2 += __shfl_xor(e2, d);
  }
  __shared__ float se[2][4];
  if (lane == 0) { se[0][wv] = e1; se[1][wv] = e2; }
  __syncthreads();
  if (t == 0) {
    float S1 = se[0][0] + se[0][1] + se[0][2] + se[0][3];
    float S2 = se[1][0] + se[1][1] + se[1][2] + se[1][3];
    float lse1 = m1 + logf(S1);
    float lse2 = m2 + logf(S2);
    partial[b] = (lse1 - s * i2g[b * 257]) + (lse2 - s * g2i[b * 257]);
  }
}

// ---------------- kernel 4: final scalar --------------------------------------------
__global__ __launch_bounds__(256) void finish_kernel(
    const float* __restrict__ partial, float* __restrict__ out)
{
  int t = threadIdx.x, lane = t & 63, wv = t >> 6;
  float v = partial[t];
  #pragma unroll
  for (int d = 1; d < 64; d <<= 1) v += __shfl_xor(v, d);
  __shared__ float sp[4];
  if (lane == 0) sp[wv] = v;
  __syncthreads();
  if (t == 0) out[0] = (sp[0] + sp[1] + sp[2] + sp[3]) * (1.0f / 512.0f);
}

extern "C" void kernel_launch(void* const* d_in, const int* in_sizes, int n_in,
                              void* d_out, int out_size, void* d_ws, size_t ws_size,
                              hipStream_t stream)
{
  const float* img = (const float*)d_in[0];
  const float* gps = (const float*)d_in[1];
  const float* lsp = (const float*)d_in[2];
  float* out = (float*)d_out;
  char* ws = (char*)d_ws;

  unsigned short* imgS = (unsigned short*)(ws);              //  8,388,608 B
  unsigned short* gpsS = (unsigned short*)(ws + 8388608);    //  4,194,304 B
  float* i2g     = (float*)(ws + 12582912);                  //    262,144 B
  float* g2i     = (float*)(ws + 12845056);                  //    262,144 B
  float* partial = (float*)(ws + 13107200);                  //      1,024 B

  norm_kernel<<<6144, 256, 0, stream>>>(img, gps, imgS, gpsS);
  pair_kernel<<<2048, 256, 0, stream>>>(imgS, gpsS, i2g, g2i);
  ce_kernel<<<256, 256, 0, stream>>>(i2g, g2i, lsp, partial);
  finish_kernel<<<1, 256, 0, stream>>>(partial, out);
}